// Round 4
// baseline (754.877 us; speedup 1.0000x reference)
//
#include <hip/hip_runtime.h>
#include <hip/hip_bf16.h>

typedef float f32x4 __attribute__((ext_vector_type(4)));
typedef short s16x8 __attribute__((ext_vector_type(8)));

#define OBS   64
#define NHID  128
#define LAT   32
#define KTOT  192
#define BB    16     // batch rows per wave/block
#define HSTR  68     // uint words per LDS h row: 272B = 16B-aligned, b64/b128 at bank floor

static __device__ __forceinline__ unsigned short f2bf(float x) {
    __hip_bfloat16 h = __float2bfloat16(x);
    return *reinterpret_cast<unsigned short*>(&h);
}
static __device__ __forceinline__ unsigned int pack2(float a, float b) {
    return ((unsigned int)f2bf(b) << 16) | (unsigned int)f2bf(a);
}
// tanh(x) = 1 - 2/(e^{2x}+1), e^{2x} = 2^{2*log2e*x}. 5 VALU ops via the HW
// v_exp_f32 (=2^x) and v_rcp_f32. Tail-safe: x>>0: exp2->inf, rcp->0, result 1;
// x<<0: exp2->0, result 1-2 = -1.
static __device__ __forceinline__ float fast_tanh(float x) {
    float e = __builtin_amdgcn_exp2f(x * 2.8853900817779268f);
    float r = __builtin_amdgcn_rcpf(e + 1.0f);
    return __builtin_fmaf(-2.0f, r, 1.0f);
}
static __device__ __forceinline__ s16x8 pack8(float4 a, float4 b) {
    s16x8 f;
    f[0]=(short)f2bf(a.x); f[1]=(short)f2bf(a.y); f[2]=(short)f2bf(a.z); f[3]=(short)f2bf(a.w);
    f[4]=(short)f2bf(b.x); f[5]=(short)f2bf(b.y); f[6]=(short)f2bf(b.z); f[7]=(short)f2bf(b.w);
    return f;
}

// One wave (64 threads) = one 16-row batch strip, full recurrence, ZERO barriers.
// W1: 8 j-tiles x 6 k-frags of A-fragments resident in VGPRs. h loops through a
// wave-private LDS roundtrip (D-layout -> B-layout); x prefetched 2 steps deep
// straight into registers (no barrier ever drains vmcnt).
__global__ __launch_bounds__(64, 1) void rnn_wave(
    const float* __restrict__ data,   // [B, T, OBS]
    const float* __restrict__ W1,     // [NHID, KTOT]
    const float* __restrict__ b1,     // [NHID]
    const float* __restrict__ Wo,     // [LAT, NHID]
    const float* __restrict__ bo,     // [LAT]
    float* __restrict__ out,          // [B, T, LAT]
    int T)
{
    __shared__ __align__(16) unsigned int hbuf[BB * HSTR];

    const int l  = threadIdx.x;
    const int b  = l & 15;        // batch col within strip / A row
    const int lg = l >> 4;        // 0..3
    const int b0 = blockIdx.x * BB;

    // ---- W1 A-frags: lane holds W1[16jt + b][32kf + 8lg + i] ----
    s16x8 w1f[8][6];
    f32x4 b1f[8];
    #pragma unroll
    for (int jt = 0; jt < 8; ++jt) {
        const float* wrow = W1 + (size_t)(jt * 16 + b) * KTOT + lg * 8;
        #pragma unroll
        for (int kf = 0; kf < 6; ++kf) {
            float4 a = *reinterpret_cast<const float4*>(wrow + kf * 32);
            float4 c = *reinterpret_cast<const float4*>(wrow + kf * 32 + 4);
            w1f[jt][kf] = pack8(a, c);
        }
        b1f[jt] = *reinterpret_cast<const f32x4*>(b1 + jt * 16 + lg * 4);
    }
    // ---- Wo A-frags ----
    s16x8 wof[2][4];
    f32x4 bof_[2];
    #pragma unroll
    for (int lt = 0; lt < 2; ++lt) {
        const float* wrow = Wo + (size_t)(lt * 16 + b) * NHID + lg * 8;
        #pragma unroll
        for (int kt = 0; kt < 4; ++kt) {
            float4 a = *reinterpret_cast<const float4*>(wrow + kt * 32);
            float4 c = *reinterpret_cast<const float4*>(wrow + kt * 32 + 4);
            wof[lt][kt] = pack8(a, c);
        }
        bof_[lt] = *reinterpret_cast<const f32x4*>(bo + lt * 16 + lg * 4);
    }

    const float* xrp  = data + (size_t)(b0 + b) * T * OBS + lg * 8;
    float*       orow = out  + (size_t)(b0 + b) * T * LAT + lg * 4;

    s16x8 hfr[4];                     // h_{t-1} B-frags (bf16), start at 0
    #pragma unroll
    for (int kf = 0; kf < 4; ++kf)
        #pragma unroll
        for (int i = 0; i < 8; ++i) hfr[kf][i] = 0;

    // prologue: x_0 synchronous, x_1 issued
    float4 pA[4], pB[4];
    s16x8  xA[2], xB[2];
    {
        pA[0] = *reinterpret_cast<const float4*>(xrp);
        pA[1] = *reinterpret_cast<const float4*>(xrp + 4);
        pA[2] = *reinterpret_cast<const float4*>(xrp + 32);
        pA[3] = *reinterpret_cast<const float4*>(xrp + 36);
        xA[0] = pack8(pA[0], pA[1]);
        xA[1] = pack8(pA[2], pA[3]);
        const float* q = xrp + (size_t)(T > 1 ? 1 : 0) * OBS;
        pB[0] = *reinterpret_cast<const float4*>(q);
        pB[1] = *reinterpret_cast<const float4*>(q + 4);
        pB[2] = *reinterpret_cast<const float4*>(q + 32);
        pB[3] = *reinterpret_cast<const float4*>(q + 36);
    }

    auto body = [&](int t, s16x8 (&xc)[2], float4 (&pn)[4], float4 (&pnn)[4],
                    s16x8 (&xn)[2]) {
        // 1. issue x_{t+2} loads (consumed NEXT body; never drained by a barrier)
        {
            int tn = (t + 2 < T) ? t + 2 : T - 1;
            const float* q = xrp + (size_t)tn * OBS;
            pnn[0] = *reinterpret_cast<const float4*>(q);
            pnn[1] = *reinterpret_cast<const float4*>(q + 4);
            pnn[2] = *reinterpret_cast<const float4*>(q + 32);
            pnn[3] = *reinterpret_cast<const float4*>(q + 36);
        }
        // 2. i2h: 8 independent 6-deep MFMA chains
        f32x4 acc[8];
        #pragma unroll
        for (int jt = 0; jt < 8; ++jt) {
            f32x4 a = b1f[jt];
            a = __builtin_amdgcn_mfma_f32_16x16x32_bf16(w1f[jt][0], xc[0], a, 0, 0, 0);
            a = __builtin_amdgcn_mfma_f32_16x16x32_bf16(w1f[jt][1], xc[1], a, 0, 0, 0);
            a = __builtin_amdgcn_mfma_f32_16x16x32_bf16(w1f[jt][2], hfr[0], a, 0, 0, 0);
            a = __builtin_amdgcn_mfma_f32_16x16x32_bf16(w1f[jt][3], hfr[1], a, 0, 0, 0);
            a = __builtin_amdgcn_mfma_f32_16x16x32_bf16(w1f[jt][4], hfr[2], a, 0, 0, 0);
            a = __builtin_amdgcn_mfma_f32_16x16x32_bf16(w1f[jt][5], hfr[3], a, 0, 0, 0);
            acc[jt] = a;
        }
        // 3. tanh -> bf16 pack -> LDS (D layout: lane holds h[16jt+4lg+r][b])
        #pragma unroll
        for (int jt = 0; jt < 8; ++jt) {
            unsigned int w0 = pack2(fast_tanh(acc[jt][0]), fast_tanh(acc[jt][1]));
            unsigned int w1 = pack2(fast_tanh(acc[jt][2]), fast_tanh(acc[jt][3]));
            *reinterpret_cast<uint2*>(&hbuf[b * HSTR + jt * 8 + lg * 2]) =
                make_uint2(w0, w1);
        }
        // 4. read back in B layout: lane gets h[b][32kf + 8lg + i]
        #pragma unroll
        for (int kf = 0; kf < 4; ++kf)
            hfr[kf] = *reinterpret_cast<const s16x8*>(&hbuf[b * HSTR + kf * 16 + lg * 4]);
        // 5. h2o from the same fragments + store out_t
        #pragma unroll
        for (int lt = 0; lt < 2; ++lt) {
            f32x4 o = bof_[lt];
            #pragma unroll
            for (int kt = 0; kt < 4; ++kt)
                o = __builtin_amdgcn_mfma_f32_16x16x32_bf16(wof[lt][kt], hfr[kt], o, 0, 0, 0);
            *reinterpret_cast<f32x4*>(orow + (size_t)t * LAT + lt * 16) = o;
        }
        // 6. convert x_{t+1} (loaded one full step ago) for next body
        xn[0] = pack8(pn[0], pn[1]);
        xn[1] = pack8(pn[2], pn[3]);
    };

    for (int t = 0; t + 1 < T; t += 2) {
        body(t,     xA, pB, pA, xB);
        body(t + 1, xB, pA, pB, xA);
    }
    if (T & 1)
        body(T - 1, xA, pB, pA, xB);
}

extern "C" void kernel_launch(void* const* d_in, const int* in_sizes, int n_in,
                              void* d_out, int out_size, void* d_ws, size_t ws_size,
                              hipStream_t stream) {
    const float* data = (const float*)d_in[0];
    const float* W1   = (const float*)d_in[1];
    const float* b1   = (const float*)d_in[2];
    const float* Wo   = (const float*)d_in[3];
    const float* bo   = (const float*)d_in[4];
    float* out = (float*)d_out;

    const int B = 4096;
    const int T = in_sizes[0] / (B * OBS);

    dim3 grid(B / BB);                 // 256 single-wave blocks -> 1 per CU
    rnn_wave<<<grid, 64, 0, stream>>>(data, W1, b1, Wo, bo, out, T);
}

// Round 10
// 518.641 us; speedup vs baseline: 1.4555x; 1.4555x over previous
//
#include <hip/hip_runtime.h>
#include <hip/hip_bf16.h>

typedef float f32x4 __attribute__((ext_vector_type(4)));
typedef short s16x8 __attribute__((ext_vector_type(8)));

#define OBS   64
#define NHID  128
#define LAT   32
#define KTOT  192
#define BB    16    // batch rows per block (one MFMA B-tile)
#define HSTR  68    // uint words per h row: 272B, 16B-aligned, 2-way bank alias (free)
#define NW    4     // waves per block, wave w owns j in [32w, 32w+32)

static __device__ __forceinline__ unsigned short f2bf(float x) {
    __hip_bfloat16 h = __float2bfloat16(x);
    return *reinterpret_cast<unsigned short*>(&h);
}
static __device__ __forceinline__ unsigned int pack2(float a, float b) {
    return ((unsigned int)f2bf(b) << 16) | (unsigned int)f2bf(a);
}
// tanh(x) = 1 - 2/(2^{2*log2e*x}+1) via HW v_exp_f32/v_rcp_f32; tail-safe.
static __device__ __forceinline__ float fast_tanh(float x) {
    float e = __builtin_amdgcn_exp2f(x * 2.8853900817779268f);
    float r = __builtin_amdgcn_rcpf(e + 1.0f);
    return __builtin_fmaf(-2.0f, r, 1.0f);
}
static __device__ __forceinline__ s16x8 pack8(float4 a, float4 b) {
    s16x8 f;
    f[0]=(short)f2bf(a.x); f[1]=(short)f2bf(a.y); f[2]=(short)f2bf(a.z); f[3]=(short)f2bf(a.w);
    f[4]=(short)f2bf(b.x); f[5]=(short)f2bf(b.y); f[6]=(short)f2bf(b.z); f[7]=(short)f2bf(b.w);
    return f;
}

// Block = one 16-row batch strip, 4 waves j-split (32 hidden units each).
// h double-buffered in LDS; ONE raw s_barrier per step with manual
// lgkmcnt(0) — vmcnt (x prefetch) is NEVER drained. h2o split over waves
// 0/1, computed one step delayed from the freshly-read h fragments.
__global__ __launch_bounds__(256, 1) void rnn_mw(
    const float* __restrict__ data,   // [B, T, OBS]
    const float* __restrict__ W1,     // [NHID, KTOT]
    const float* __restrict__ b1,     // [NHID]
    const float* __restrict__ Wo,     // [LAT, NHID]
    const float* __restrict__ bo,     // [LAT]
    float* __restrict__ out,          // [B, T, LAT]
    int T)
{
    __shared__ __align__(16) unsigned int hbuf[2][BB * HSTR];

    const int tid = threadIdx.x;
    const int wid = tid >> 6;
    const int l   = tid & 63;
    const int b   = l & 15;       // batch col within strip
    const int lg  = l >> 4;       // 0..3
    const int b0  = blockIdx.x * BB;
    const int jt0 = wid * 2;      // this wave's first 16-wide j tile

    // ---- W1 A-frags for this wave's 2 j-tiles ----
    s16x8 w1f[2][6];
    f32x4 b1f[2];
    #pragma unroll
    for (int jtl = 0; jtl < 2; ++jtl) {
        const float* wrow = W1 + (size_t)((jt0 + jtl) * 16 + b) * KTOT + lg * 8;
        #pragma unroll
        for (int kf = 0; kf < 6; ++kf) {
            float4 a = *reinterpret_cast<const float4*>(wrow + kf * 32);
            float4 c = *reinterpret_cast<const float4*>(wrow + kf * 32 + 4);
            w1f[jtl][kf] = pack8(a, c);
        }
        b1f[jtl] = *reinterpret_cast<const f32x4*>(b1 + (jt0 + jtl) * 16 + lg * 4);
    }
    // ---- Wo A-frags: wave 0 -> lt 0, wave 1 -> lt 1 ----
    s16x8 wof[4];
    f32x4 bofv;
    if (wid < 2) {
        const float* wrow = Wo + (size_t)(wid * 16 + b) * NHID + lg * 8;
        #pragma unroll
        for (int kt = 0; kt < 4; ++kt) {
            float4 a = *reinterpret_cast<const float4*>(wrow + kt * 32);
            float4 c = *reinterpret_cast<const float4*>(wrow + kt * 32 + 4);
            wof[kt] = pack8(a, c);
        }
        bofv = *reinterpret_cast<const f32x4*>(bo + wid * 16 + lg * 4);
    }

    // zero h buffer 0 (h_{-1} = 0)
    for (int i = tid; i < BB * HSTR; i += 256) hbuf[0][i] = 0;
    __syncthreads();   // init-only full barrier (before any prefetch is live)

    const float* xrp  = data + (size_t)(b0 + b) * T * OBS + lg * 8;
    float*       orow = out  + (size_t)(b0 + b) * T * LAT + wid * 16 + lg * 4;

    // x prefetch, depth 2 (register), preserved across raw barriers
    float4 pA[4], pB[4];
    s16x8  xA[2], xB[2];
    {
        pA[0] = *reinterpret_cast<const float4*>(xrp);
        pA[1] = *reinterpret_cast<const float4*>(xrp + 4);
        pA[2] = *reinterpret_cast<const float4*>(xrp + 32);
        pA[3] = *reinterpret_cast<const float4*>(xrp + 36);
        xA[0] = pack8(pA[0], pA[1]);
        xA[1] = pack8(pA[2], pA[3]);
        const float* q = xrp + (size_t)(T > 1 ? 1 : 0) * OBS;
        pB[0] = *reinterpret_cast<const float4*>(q);
        pB[1] = *reinterpret_cast<const float4*>(q + 4);
        pB[2] = *reinterpret_cast<const float4*>(q + 32);
        pB[3] = *reinterpret_cast<const float4*>(q + 36);
    }

    auto body = [&](int t, const unsigned int* cur, unsigned int* nxt,
                    s16x8 (&xc)[2], float4 (&pn)[4], float4 (&pnn)[4],
                    s16x8 (&xn)[2]) {
        // read h_{t-1} B-frags (full 128 wide) from cur
        s16x8 hfr[4];
        #pragma unroll
        for (int kf = 0; kf < 4; ++kf)
            hfr[kf] = *reinterpret_cast<const s16x8*>(&cur[b * HSTR + kf * 16 + lg * 4]);

        // issue x_{t+2} loads (consumed end of NEXT body; survive the barrier)
        {
            int tn = (t + 2 < T) ? t + 2 : T - 1;
            const float* q = xrp + (size_t)tn * OBS;
            pnn[0] = *reinterpret_cast<const float4*>(q);
            pnn[1] = *reinterpret_cast<const float4*>(q + 4);
            pnn[2] = *reinterpret_cast<const float4*>(q + 32);
            pnn[3] = *reinterpret_cast<const float4*>(q + 36);
        }

        // i2h, kf-outer (2-way ILP); x-part first (issues under the ds_read wait)
        f32x4 a0 = b1f[0], a1 = b1f[1];
        a0 = __builtin_amdgcn_mfma_f32_16x16x32_bf16(w1f[0][0], xc[0], a0, 0, 0, 0);
        a1 = __builtin_amdgcn_mfma_f32_16x16x32_bf16(w1f[1][0], xc[0], a1, 0, 0, 0);
        a0 = __builtin_amdgcn_mfma_f32_16x16x32_bf16(w1f[0][1], xc[1], a0, 0, 0, 0);
        a1 = __builtin_amdgcn_mfma_f32_16x16x32_bf16(w1f[1][1], xc[1], a1, 0, 0, 0);
        #pragma unroll
        for (int kf = 0; kf < 4; ++kf) {
            a0 = __builtin_amdgcn_mfma_f32_16x16x32_bf16(w1f[0][2 + kf], hfr[kf], a0, 0, 0, 0);
            a1 = __builtin_amdgcn_mfma_f32_16x16x32_bf16(w1f[1][2 + kf], hfr[kf], a1, 0, 0, 0);
        }

        // h2o for step t-1 (uses hfr = h_{t-1}); waves 0/1 only, off critical path
        if (wid < 2 && t > 0) {
            f32x4 o = bofv;
            #pragma unroll
            for (int kt = 0; kt < 4; ++kt)
                o = __builtin_amdgcn_mfma_f32_16x16x32_bf16(wof[kt], hfr[kt], o, 0, 0, 0);
            *reinterpret_cast<f32x4*>(orow + (size_t)(t - 1) * LAT) = o;
        }

        // tanh -> bf16 -> LDS (D layout) into nxt
        {
            unsigned int w00 = pack2(fast_tanh(a0[0]), fast_tanh(a0[1]));
            unsigned int w01 = pack2(fast_tanh(a0[2]), fast_tanh(a0[3]));
            unsigned int w10 = pack2(fast_tanh(a1[0]), fast_tanh(a1[1]));
            unsigned int w11 = pack2(fast_tanh(a1[2]), fast_tanh(a1[3]));
            *reinterpret_cast<uint2*>(&nxt[b * HSTR + jt0 * 8 + lg * 2]) =
                make_uint2(w00, w01);
            *reinterpret_cast<uint2*>(&nxt[b * HSTR + (jt0 + 1) * 8 + lg * 2]) =
                make_uint2(w10, w11);
        }

        // convert x_{t+1} (issued one body ago) for the next body
        xn[0] = pack8(pn[0], pn[1]);
        xn[1] = pack8(pn[2], pn[3]);

        // RAW-only sync: drain LDS, NOT vmcnt; x prefetch stays in flight
        asm volatile("s_waitcnt lgkmcnt(0)" ::: "memory");
        __builtin_amdgcn_s_barrier();
        asm volatile("" ::: "memory");
    };

    unsigned int* h0 = hbuf[0];
    unsigned int* h1 = hbuf[1];
    for (int t = 0; t + 1 < T; t += 2) {
        body(t,     h0, h1, xA, pB, pA, xB);
        body(t + 1, h1, h0, xB, pA, pB, xA);
    }
    if (T & 1) {
        body(T - 1, h0, h1, xA, pB, pA, xB);
        unsigned int* tmp = h0; h0 = h1; h1 = tmp;
    }

    // epilogue: out_{T-1} from h_{T-1} (now in h0; last body's barrier ordered it)
    if (wid < 2) {
        s16x8 hfr[4];
        #pragma unroll
        for (int kf = 0; kf < 4; ++kf)
            hfr[kf] = *reinterpret_cast<const s16x8*>(&h0[b * HSTR + kf * 16 + lg * 4]);
        f32x4 o = bofv;
        #pragma unroll
        for (int kt = 0; kt < 4; ++kt)
            o = __builtin_amdgcn_mfma_f32_16x16x32_bf16(wof[kt], hfr[kt], o, 0, 0, 0);
        *reinterpret_cast<f32x4*>(orow + (size_t)(T - 1) * LAT) = o;
    }
}

extern "C" void kernel_launch(void* const* d_in, const int* in_sizes, int n_in,
                              void* d_out, int out_size, void* d_ws, size_t ws_size,
                              hipStream_t stream) {
    const float* data = (const float*)d_in[0];
    const float* W1   = (const float*)d_in[1];
    const float* b1   = (const float*)d_in[2];
    const float* Wo   = (const float*)d_in[3];
    const float* bo   = (const float*)d_in[4];
    float* out = (float*)d_out;

    const int B = 4096;
    const int T = in_sizes[0] / (B * OBS);

    dim3 grid(B / BB);                   // 256 blocks, 4 waves each -> 1 wave/SIMD
    rnn_mw<<<grid, 256, 0, stream>>>(data, W1, b1, Wo, bo, out, T);
}